// Round 6
// baseline (175.847 us; speedup 1.0000x reference)
//
#include <hip/hip_runtime.h>
#include <hip/hip_bf16.h>
#include <math.h>

#define NN 4096

typedef __attribute__((ext_vector_type(8))) short s8v;        // 8 bf16 = 16B
typedef __attribute__((ext_vector_type(4))) float f4v;        // MFMA accum
typedef __attribute__((ext_vector_type(4))) unsigned int u32x4;
typedef __attribute__((ext_vector_type(2))) unsigned int u32x2;
typedef unsigned short u16;

static __device__ __forceinline__ f4v MFMA16(s8v a, s8v b, f4v c) {
  return __builtin_amdgcn_mfma_f32_16x16x32_bf16(a, b, c, 0, 0, 0);
}
static __device__ __forceinline__ u16 f2bf(float f) {
  union { float f; unsigned int u; } v; v.f = f;
  unsigned int r = v.u + 0x7fffu + ((v.u >> 16) & 1u);
  return (u16)(r >> 16);
}
static __device__ __forceinline__ float bf2f(u16 u) {
  union { unsigned int u; float f; } v; v.u = ((unsigned int)u) << 16;
  return v.f;
}
static __device__ __forceinline__ unsigned int cvt2u(float lo, float hi) {
  __hip_bfloat162 h = __float22bfloat162_rn(make_float2(lo, hi));
  union { __hip_bfloat162 b; unsigned int u; } c; c.b = h; return c.u;
}

// swizzled byte offsets: 256B rows and 128B rows
#define SW(row, byte)  ((row) * 256 + ((byte) ^ (((row) & 7) << 4)))

// ws regions (u16 offsets). Fragment layout: base + ((mt*4 + kt)*64 + lane)*8 + j
#define FA_OFF 0         // [q1;k1;v1]   24 tiles
#define FB_OFF 49152     // [q2;k2;v2]   24 tiles
#define FC_OFF 98304     // [xm1 (0-7); ErelB (8-15)] 16 tiles
#define FD_OFF 131072    // ErelT        8 tiles

// ---------------- prep: fragment all weights + Erel (both layouts) ----------------
__global__ void prep_kernel(const float* __restrict__ qw1, const float* __restrict__ kw1,
                            const float* __restrict__ vw1, const float* __restrict__ qw2,
                            const float* __restrict__ kw2, const float* __restrict__ vw2,
                            const float* __restrict__ xmw1,
                            const float* __restrict__ t_w, const float* __restrict__ t_b,
                            u16* __restrict__ wsb) {
  const int b = blockIdx.x, tid = threadIdx.x;
  const int kt = tid >> 6, l = tid & 63, lr = l & 15, lk = l >> 4;
  if (b < 56) {
    const float* W; int mt; u16* base;
    if (b < 24)      { base = wsb + FA_OFF; mt = b;      W = (b < 8) ? qw1 : (b < 16) ? kw1 : vw1; }
    else if (b < 48) { base = wsb + FB_OFF; mt = b - 24; W = (mt < 8) ? qw2 : (mt < 16) ? kw2 : vw2; }
    else             { base = wsb + FC_OFF; mt = b - 48; W = xmw1; }
    const int ch = (mt & 7) * 16;
    u16 o[8];
#pragma unroll
    for (int j = 0; j < 8; ++j) o[j] = f2bf(W[(kt * 32 + lk * 8 + j) * 128 + ch + lr]);
    u32x4 pk;
#pragma unroll
    for (int i = 0; i < 4; ++i) pk[i] = (unsigned int)o[2 * i] | ((unsigned int)o[2 * i + 1] << 16);
    *(u32x4*)&base[((mt * 4 + kt) * 64 + l) * 8] = pk;
  } else {
    const int rt = b - 56;
    const int r = rt * 16 + lr;
    const float rel = (float)(r - 63);
    const int h0 = kt * 32 + lk * 8;
    float acc[8];
#pragma unroll
    for (int j = 0; j < 8; ++j) acc[j] = t_b[h0 + j];
    const float C = -logf(10000.0f) / 63.0f;
    for (int i = 0; i < 64; ++i) {
      float f = expf((float)i * C);
      float a = rel * f;
      float sn = sinf(a), cs = cosf(a);
#pragma unroll
      for (int j = 0; j < 8; ++j) acc[j] = fmaf(sn, t_w[i * 128 + h0 + j], acc[j]);
#pragma unroll
      for (int j = 0; j < 8; ++j) acc[j] = fmaf(cs, t_w[(i + 64) * 128 + h0 + j], acc[j]);
    }
    u16 o[8];
#pragma unroll
    for (int j = 0; j < 8; ++j) o[j] = f2bf(acc[j]);
    u32x4 pk;
#pragma unroll
    for (int i = 0; i < 4; ++i) pk[i] = (unsigned int)o[2 * i] | ((unsigned int)o[2 * i + 1] << 16);
    *(u32x4*)&wsb[FC_OFF + (((8 + rt) * 4 + kt) * 64 + l) * 8] = pk;
    const int ct = h0 >> 4, lrp = h0 & 15;
    const int ktp = r >> 5, lkp = (r >> 3) & 3, jp = r & 7;
#pragma unroll
    for (int j = 0; j < 8; ++j)
      wsb[FD_OFF + ((ct * 4 + ktp) * 64 + lkp * 16 + lrp + j) * 8 + jp] = o[j];
  }
}

// one 16ch x 64t tile: A = pre-fragmented global, B = LDS SW; out bf16 -> Ol[t][ocol..]
template <bool SILU, bool HASB>
__device__ __forceinline__ void tile_gemm(const u16* __restrict__ fr,
                                          const unsigned char* Bl, unsigned char* Ol,
                                          const float* __restrict__ bias,
                                          int ocol, int l, int lr, int lk, int swm,
                                          const int* rb) {
  s8v a[4];
#pragma unroll
  for (int kt = 0; kt < 4; ++kt) a[kt] = *(const s8v*)&fr[(kt * 64 + l) * 8];
  float bj[4];
#pragma unroll
  for (int j = 0; j < 4; ++j) bj[j] = HASB ? bias[lk * 4 + j] : 0.f;
  f4v acc[4];
#pragma unroll
  for (int ni = 0; ni < 4; ++ni)
#pragma unroll
    for (int j = 0; j < 4; ++j) acc[ni][j] = bj[j];
#pragma unroll
  for (int kt = 0; kt < 4; ++kt)
#pragma unroll
    for (int ni = 0; ni < 4; ++ni)
      acc[ni] = MFMA16(a[kt], *(const s8v*)(Bl + ni * 4096 + rb[kt]), acc[ni]);
  const int ob = lr * 256 + ((ocol + lk * 8) ^ swm);
#pragma unroll
  for (int ni = 0; ni < 4; ++ni) {
    float v0 = acc[ni][0], v1 = acc[ni][1], v2 = acc[ni][2], v3 = acc[ni][3];
    if (SILU) {
      v0 *= __builtin_amdgcn_rcpf(1.0f + __expf(-v0));
      v1 *= __builtin_amdgcn_rcpf(1.0f + __expf(-v1));
      v2 *= __builtin_amdgcn_rcpf(1.0f + __expf(-v2));
      v3 *= __builtin_amdgcn_rcpf(1.0f + __expf(-v3));
    }
    u32x2 st; st[0] = cvt2u(v0, v1); st[1] = cvt2u(v2, v3);
    *(u32x2*)(Ol + ni * 4096 + ob) = st;
  }
}

// LDS slots (16KB each, 80KB total -> 2 blocks/CU); liveness:
// S0: tok -> V                S1: HQ -> K          S2: HK -> {ALP(8K) | Y(2K)@8192 | XLS@10240}
// S3: HV -> {qEc(8K) | VXP(2K)@8192} -> vT         S4: Q -> A2
__launch_bounds__(512, 4)
__global__ void et_main(const float* __restrict__ xg, const float* __restrict__ hg,
                        const u16* __restrict__ wsb,
                        const float* __restrict__ qb1, const float* __restrict__ qb2,
                        const float* __restrict__ kb1, const float* __restrict__ kb2,
                        const float* __restrict__ vb1, const float* __restrict__ vb2,
                        const float* __restrict__ xmb1, const float* __restrict__ xmw2,
                        const float* __restrict__ xmb2,
                        float* __restrict__ xout, float* __restrict__ hout) {
  __shared__ __align__(16) unsigned char smem[81920];
  unsigned char* S0 = smem;
  unsigned char* S1 = smem + 16384;
  unsigned char* S2 = smem + 32768;
  unsigned char* S3 = smem + 49152;
  unsigned char* S4 = smem + 65536;
  unsigned char* ALP = S2;
  unsigned char* YB  = S2 + 8192;
  float* XLS = (float*)(S2 + 10240);
  float* VXP = (float*)(S3 + 8192);

  const u16* FA = wsb + FA_OFF;
  const u16* FB = wsb + FB_OFF;
  const u16* FC = wsb + FC_OFF;
  const u16* FD = wsb + FD_OFF;

  const int tid = threadIdx.x;
  const int l = tid & 63;
  const int lr = l & 15, lk = l >> 4;
  const int w = __builtin_amdgcn_readfirstlane(tid >> 6);
  const int n = blockIdx.x;
  const size_t hbase = (size_t)n * 8192;
  const int swm = (lr & 7) << 4;
  // hoisted LDS read bases: full-row tiles (256B rows) and half-row tiles (128B rows)
  int rb[4], hrb[2];
#pragma unroll
  for (int kt = 0; kt < 4; ++kt) rb[kt] = lr * 256 + ((kt * 64 + lk * 16) ^ swm);
#pragma unroll
  for (int kt = 0; kt < 2; ++kt) hrb[kt] = lr * 128 + ((kt * 64 + lk * 16) ^ swm);

  // ---- P0: tok -> S0 ----
  {
    int t = tid & 63, c0 = (tid >> 6) * 2;
#pragma unroll
    for (int cc = 0; cc < 2; ++cc) {
      int c = c0 + cc;
      float hv[8];
#pragma unroll
      for (int j = 0; j < 8; ++j) hv[j] = hg[hbase + (size_t)(c * 8 + j) * 64 + t];
      u32x4 pk;
#pragma unroll
      for (int j = 0; j < 4; ++j) pk[j] = cvt2u(hv[2 * j], hv[2 * j + 1]);
      *(u32x4*)(S0 + SW(t, c * 16)) = pk;
    }
  }
  __syncthreads();

  // ---- P1: q1,k1,v1 @ tok -> HQ(S1), HK(S2), HV(S3) ----
  tile_gemm<true, true>(FA + (w)      * 2048, S0, S1, qb1 + w * 16, w * 32, l, lr, lk, swm, rb);
  tile_gemm<true, true>(FA + (w + 8)  * 2048, S0, S2, kb1 + w * 16, w * 32, l, lr, lk, swm, rb);
  tile_gemm<true, true>(FA + (w + 16) * 2048, S0, S3, vb1 + w * 16, w * 32, l, lr, lk, swm, rb);
  __syncthreads();

  // ---- P2: q2 (HQ->Q:S4), v2 (HV->V:S0) ----
  tile_gemm<false, true>(FB + (w)      * 2048, S1, S4, qb2 + w * 16, w * 32, l, lr, lk, swm, rb);
  tile_gemm<false, true>(FB + (w + 16) * 2048, S3, S0, vb2 + w * 16, w * 32, l, lr, lk, swm, rb);
  __syncthreads();

  // ---- P3: k2 (HK->K:S1); qEc (Q->S3 compact); xm (V) -> vx partials -> VXP ----
  tile_gemm<false, true>(FB + (w + 8) * 2048, S2, S1, kb2 + w * 16, w * 32, l, lr, lk, swm, rb);
  { // qE tile w: r = w*16+lk*4+j, t = ni*16+lr; keep i = r-t in [0,64) -> qEc[t][i]
    const u16* fr = FC + (8 + w) * 2048;
    s8v a[4];
#pragma unroll
    for (int kt = 0; kt < 4; ++kt) a[kt] = *(const s8v*)&fr[(kt * 64 + l) * 8];
    f4v acc[4];
#pragma unroll
    for (int ni = 0; ni < 4; ++ni)
#pragma unroll
      for (int j = 0; j < 4; ++j) acc[ni][j] = 0.f;
#pragma unroll
    for (int kt = 0; kt < 4; ++kt)
#pragma unroll
      for (int ni = 0; ni < 4; ++ni)
        acc[ni] = MFMA16(a[kt], *(const s8v*)(S4 + ni * 4096 + rb[kt]), acc[ni]);
    const int rbase = w * 16 + lk * 4;
#pragma unroll
    for (int ni = 0; ni < 4; ++ni) {
      int t = ni * 16 + lr;
      unsigned int p0 = cvt2u(acc[ni][0], acc[ni][1]);
      unsigned int p1 = cvt2u(acc[ni][2], acc[ni][3]);
      int i0 = rbase - t;
      if ((unsigned)(i0 + 0) < 64u) *(u16*)(S3 + t * 128 + ((2 * (i0 + 0)) ^ swm)) = (u16)(p0 & 0xffffu);
      if ((unsigned)(i0 + 1) < 64u) *(u16*)(S3 + t * 128 + ((2 * (i0 + 1)) ^ swm)) = (u16)(p0 >> 16);
      if ((unsigned)(i0 + 2) < 64u) *(u16*)(S3 + t * 128 + ((2 * (i0 + 2)) ^ swm)) = (u16)(p1 & 0xffffu);
      if ((unsigned)(i0 + 3) < 64u) *(u16*)(S3 + t * 128 + ((2 * (i0 + 3)) ^ swm)) = (u16)(p1 >> 16);
    }
  }
  { // xm tile w over V(S0): vx partials
    const u16* fr = FC + w * 2048;
    s8v a[4];
#pragma unroll
    for (int kt = 0; kt < 4; ++kt) a[kt] = *(const s8v*)&fr[(kt * 64 + l) * 8];
    float bj[4], w2[4];
#pragma unroll
    for (int j = 0; j < 4; ++j) { bj[j] = xmb1[w * 16 + lk * 4 + j]; w2[j] = xmw2[w * 16 + lk * 4 + j]; }
    f4v acc[4];
#pragma unroll
    for (int ni = 0; ni < 4; ++ni)
#pragma unroll
      for (int j = 0; j < 4; ++j) acc[ni][j] = bj[j];
#pragma unroll
    for (int kt = 0; kt < 4; ++kt)
#pragma unroll
      for (int ni = 0; ni < 4; ++ni)
        acc[ni] = MFMA16(a[kt], *(const s8v*)(S0 + ni * 4096 + rb[kt]), acc[ni]);
#pragma unroll
    for (int ni = 0; ni < 4; ++ni) {
      float s = 0.f;
#pragma unroll
      for (int j = 0; j < 4; ++j) {
        float v = acc[ni][j];
        v *= __builtin_amdgcn_rcpf(1.0f + __expf(-v));
        s = fmaf(v, w2[j], s);
      }
      s += __shfl_xor(s, 16, 64);
      s += __shfl_xor(s, 32, 64);
      if (l < 16) VXP[w * 64 + ni * 16 + l] = s;
    }
  }
  __syncthreads();

  // ---- P4: waves 0-3: scores (full s-row in regs) + softmax + ALP; wave 4: vx/Y/XLS; wave 5: zero Y tail ----
  unsigned int apk[8];
  if (w < 4) {
    const int n0 = w * 16, t = n0 + lr;
    s8v bq[4];
#pragma unroll
    for (int kt = 0; kt < 4; ++kt) bq[kt] = *(const s8v*)(S4 + n0 * 256 + rb[kt]);
    f4v acc[4];
#pragma unroll
    for (int mi = 0; mi < 4; ++mi)
#pragma unroll
      for (int j = 0; j < 4; ++j) acc[mi][j] = 0.f;
#pragma unroll
    for (int kt = 0; kt < 4; ++kt)
#pragma unroll
      for (int mi = 0; mi < 4; ++mi)
        acc[mi] = MFMA16(*(const s8v*)(S1 + mi * 4096 + rb[kt]), bq[kt], acc[mi]);
    float e[4][4];
#pragma unroll
    for (int mi = 0; mi < 4; ++mi) {   // add qE: i = 63-s, one aligned u32x2 per mi
      u32x2 qv = *(const u32x2*)(S3 + t * 128 + ((120 - 32 * mi - 8 * lk) ^ swm));
      e[mi][3] = acc[mi][3] + bf2f((u16)(qv[0] & 0xffffu));
      e[mi][2] = acc[mi][2] + bf2f((u16)(qv[0] >> 16));
      e[mi][1] = acc[mi][1] + bf2f((u16)(qv[1] & 0xffffu));
      e[mi][0] = acc[mi][0] + bf2f((u16)(qv[1] >> 16));
    }
    float m = e[0][0];
#pragma unroll
    for (int mi = 0; mi < 4; ++mi)
#pragma unroll
      for (int j = 0; j < 4; ++j) m = fmaxf(m, e[mi][j]);
    m = fmaxf(m, __shfl_xor(m, 16, 64));
    m = fmaxf(m, __shfl_xor(m, 32, 64));
    float s = 0.f;
#pragma unroll
    for (int mi = 0; mi < 4; ++mi)
#pragma unroll
      for (int j = 0; j < 4; ++j) { e[mi][j] = __expf(e[mi][j] - m); s += e[mi][j]; }
    s += __shfl_xor(s, 16, 64);
    s += __shfl_xor(s, 32, 64);
    float inv = __builtin_amdgcn_rcpf(s);
#pragma unroll
    for (int mi = 0; mi < 4; ++mi) {
      apk[2 * mi]     = cvt2u(e[mi][0] * inv, e[mi][1] * inv);
      apk[2 * mi + 1] = cvt2u(e[mi][2] * inv, e[mi][3] * inv);
      u32x2 st; st[0] = apk[2 * mi]; st[1] = apk[2 * mi + 1];
      *(u32x2*)(ALP + t * 128 + ((mi * 32 + lk * 8) ^ swm)) = st;
    }
  } else if (w == 4) {
    int t = l;
    float vx = xmb2[0];
#pragma unroll
    for (int wv = 0; wv < 8; ++wv) vx += VXP[wv * 64 + t];
    float x0 = xg[n * 192 + t], x1 = xg[n * 192 + 64 + t], x2 = xg[n * 192 + 128 + t];
    XLS[t] = x0; XLS[64 + t] = x1; XLS[128 + t] = x2;
    unsigned int p0 = cvt2u(vx, vx * x0), p1 = cvt2u(vx * x1, vx * x2);
    *(u16*)(YB + 0   + ((2 * t) ^ 0))  = (u16)(p0 & 0xffffu);
    *(u16*)(YB + 128 + ((2 * t) ^ 16)) = (u16)(p0 >> 16);
    *(u16*)(YB + 256 + ((2 * t) ^ 32)) = (u16)(p1 & 0xffffu);
    *(u16*)(YB + 384 + ((2 * t) ^ 48)) = (u16)(p1 >> 16);
  } else if (w == 5) {
    u32x4 zz; zz[0] = zz[1] = zz[2] = zz[3] = 0;
    *(u32x4*)(YB + 512 + l * 16) = zz;
    if (l < 32) *(u32x4*)(YB + 1536 + l * 16) = zz;
  }
  __syncthreads();

  // ---- P5: waves 0-3: A2 zero + band scatter (own rows); waves 4-7: V transpose -> vT(S3) ----
  if (w < 4) {
    const int n0 = w * 16, t = n0 + lr;
    u32x4 zz; zz[0] = zz[1] = zz[2] = zz[3] = 0;
#pragma unroll
    for (int c = 0; c < 4; ++c) *(u32x4*)(S4 + t * 256 + lk * 64 + c * 16) = zz;
#pragma unroll
    for (int mi = 0; mi < 4; ++mi) {
      int rr = t + 63 - mi * 16 - lk * 4;   // r for j=0
      *(u16*)(S4 + t * 256 + ((2 * (rr - 0)) ^ swm)) = (u16)(apk[2 * mi] & 0xffffu);
      *(u16*)(S4 + t * 256 + ((2 * (rr - 1)) ^ swm)) = (u16)(apk[2 * mi] >> 16);
      *(u16*)(S4 + t * 256 + ((2 * (rr - 2)) ^ swm)) = (u16)(apk[2 * mi + 1] & 0xffffu);
      *(u16*)(S4 + t * 256 + ((2 * (rr - 3)) ^ swm)) = (u16)(apk[2 * mi + 1] >> 16);
    }
  } else {
    const int u = w - 4;
    const int t0 = (u & 1) * 32;
    const int c = ((u >> 1) << 6) + l;
    unsigned int pk[16];
#pragma unroll
    for (int i2 = 0; i2 < 16; ++i2) {
      int t = t0 + 2 * i2;
      u16 v0 = *(const u16*)(S0 + t * 256 + ((2 * c) ^ ((t & 7) << 4)));
      u16 v1 = *(const u16*)(S0 + (t + 1) * 256 + ((2 * c) ^ (((t + 1) & 7) << 4)));
      pk[i2] = (unsigned int)v0 | ((unsigned int)v1 << 16);
    }
    const int cm = (c & 7) << 4;
#pragma unroll
    for (int cc = 0; cc < 4; ++cc) {
      u32x4 st; st[0] = pk[4 * cc]; st[1] = pk[4 * cc + 1]; st[2] = pk[4 * cc + 2]; st[3] = pk[4 * cc + 3];
      *(u32x4*)(S3 + c * 128 + ((t0 * 2 + cc * 16) ^ cm)) = st;
    }
  }
  __syncthreads();

  // ---- P6: dh = alpha@v + A2@Erel ; h_out = h + dh ; waves 0-3: x mini-GEMM ----
  {
    const int m0 = w * 16;
    float hld[16];
#pragma unroll
    for (int ni = 0; ni < 4; ++ni) {
      size_t base = hbase + (size_t)(m0 + lk * 4) * 64 + ni * 16 + lr;
#pragma unroll
      for (int j = 0; j < 4; ++j) hld[ni * 4 + j] = hg[base + j * 64];
    }
    f4v acc[4];
#pragma unroll
    for (int ni = 0; ni < 4; ++ni)
#pragma unroll
      for (int j = 0; j < 4; ++j) acc[ni][j] = 0.f;
#pragma unroll
    for (int kt = 0; kt < 2; ++kt) {
      s8v a = *(const s8v*)(S3 + w * 2048 + hrb[kt]);
#pragma unroll
      for (int ni = 0; ni < 4; ++ni)
        acc[ni] = MFMA16(a, *(const s8v*)(ALP + ni * 2048 + hrb[kt]), acc[ni]);
    }
    const u16* fd = FD + w * 2048;
#pragma unroll
    for (int kt = 0; kt < 4; ++kt) {
      s8v a = *(const s8v*)&fd[(kt * 64 + l) * 8];
#pragma unroll
      for (int ni = 0; ni < 4; ++ni)
        acc[ni] = MFMA16(a, *(const s8v*)(S4 + ni * 4096 + rb[kt]), acc[ni]);
    }
#pragma unroll
    for (int ni = 0; ni < 4; ++ni) {
      size_t base = hbase + (size_t)(m0 + lk * 4) * 64 + ni * 16 + lr;
#pragma unroll
      for (int j = 0; j < 4; ++j) hout[base + j * 64] = hld[ni * 4 + j] + acc[ni][j];
    }
    if (w < 4) {
      f4v xa;
#pragma unroll
      for (int j = 0; j < 4; ++j) xa[j] = 0.f;
#pragma unroll
      for (int kt = 0; kt < 2; ++kt)
        xa = MFMA16(*(const s8v*)(YB + hrb[kt]),
                    *(const s8v*)(ALP + w * 2048 + hrb[kt]), xa);
      if (lk == 0) {
        int t = w * 16 + lr;
        float a1 = xa[0];
#pragma unroll
        for (int d = 0; d < 3; ++d) {
          float xv = XLS[d * 64 + t];
          xout[n * 192 + d * 64 + t] = fmaf(xv, a1, xv) - xa[1 + d];
        }
      }
    }
  }
}

extern "C" void kernel_launch(void* const* d_in, const int* in_sizes, int n_in,
                              void* d_out, int out_size, void* d_ws, size_t ws_size,
                              hipStream_t stream) {
  const float* xg   = (const float*)d_in[0];
  const float* hg   = (const float*)d_in[1];
  const float* qw1  = (const float*)d_in[2];
  const float* qb1  = (const float*)d_in[3];
  const float* qw2  = (const float*)d_in[4];
  const float* qb2  = (const float*)d_in[5];
  const float* kw1  = (const float*)d_in[6];
  const float* kb1  = (const float*)d_in[7];
  const float* kw2  = (const float*)d_in[8];
  const float* kb2  = (const float*)d_in[9];
  const float* vw1  = (const float*)d_in[10];
  const float* vb1  = (const float*)d_in[11];
  const float* vw2  = (const float*)d_in[12];
  const float* vb2  = (const float*)d_in[13];
  const float* xmw1 = (const float*)d_in[14];
  const float* xmb1 = (const float*)d_in[15];
  const float* xmw2 = (const float*)d_in[16];
  const float* xmb2 = (const float*)d_in[17];
  const float* t_w  = (const float*)d_in[18];
  const float* t_b  = (const float*)d_in[19];

  u16* wsb = (u16*)d_ws;   // 294912 B
  float* xout = (float*)d_out;
  float* hout = xout + (size_t)NN * 192;

  prep_kernel<<<64, 256, 0, stream>>>(qw1, kw1, vw1, qw2, kw2, vw2, xmw1, t_w, t_b, wsb);
  et_main<<<NN, 512, 0, stream>>>(xg, hg, wsb,
                                  qb1, qb2, kb1, kb2, vb1, vb2, xmb1, xmw2, xmb2,
                                  xout, hout);
}

// Round 7
// 170.331 us; speedup vs baseline: 1.0324x; 1.0324x over previous
//
#include <hip/hip_runtime.h>
#include <hip/hip_bf16.h>
#include <math.h>

#define NN 4096

typedef __attribute__((ext_vector_type(8))) short s8v;        // 8 bf16 = 16B
typedef __attribute__((ext_vector_type(4))) float f4v;        // MFMA accum
typedef __attribute__((ext_vector_type(4))) unsigned int u32x4;
typedef __attribute__((ext_vector_type(2))) unsigned int u32x2;
typedef unsigned short u16;

static __device__ __forceinline__ f4v MFMA16(s8v a, s8v b, f4v c) {
  return __builtin_amdgcn_mfma_f32_16x16x32_bf16(a, b, c, 0, 0, 0);
}
static __device__ __forceinline__ u16 f2bf(float f) {
  union { float f; unsigned int u; } v; v.f = f;
  unsigned int r = v.u + 0x7fffu + ((v.u >> 16) & 1u);
  return (u16)(r >> 16);
}
static __device__ __forceinline__ float bf2f(u16 u) {
  union { unsigned int u; float f; } v; v.u = ((unsigned int)u) << 16;
  return v.f;
}
static __device__ __forceinline__ unsigned int cvt2u(float lo, float hi) {
  __hip_bfloat162 h = __float22bfloat162_rn(make_float2(lo, hi));
  union { __hip_bfloat162 b; unsigned int u; } c; c.b = h; return c.u;
}
static __device__ __forceinline__ float silu(float v) {
  return v * __builtin_amdgcn_rcpf(1.0f + __expf(-v));
}

#define SW(row, byte)  ((row) * 256 + ((byte) ^ (((row) & 7) << 4)))

// ws regions (u16 offsets). Fragment layout: base + tile*2048 + kt*512 + l*8
#define FA_OFF 0         // [q1;k1;v1]   24 tiles
#define FB_OFF 49152     // [q2;k2;v2]   24 tiles
#define FC_OFF 98304     // [xm1 (0-7); ErelB (8-15)] 16 tiles
#define FD_OFF 131072    // ErelT        8 tiles

// ---------------- prep: fragment all weights + Erel (both layouts) ----------------
__global__ void prep_kernel(const float* __restrict__ qw1, const float* __restrict__ kw1,
                            const float* __restrict__ vw1, const float* __restrict__ qw2,
                            const float* __restrict__ kw2, const float* __restrict__ vw2,
                            const float* __restrict__ xmw1,
                            const float* __restrict__ t_w, const float* __restrict__ t_b,
                            u16* __restrict__ wsb) {
  const int b = blockIdx.x, tid = threadIdx.x;
  const int kt = tid >> 6, l = tid & 63, lr = l & 15, lk = l >> 4;
  if (b < 56) {
    const float* W; int mt; u16* base;
    if (b < 24)      { base = wsb + FA_OFF; mt = b;      W = (b < 8) ? qw1 : (b < 16) ? kw1 : vw1; }
    else if (b < 48) { base = wsb + FB_OFF; mt = b - 24; W = (mt < 8) ? qw2 : (mt < 16) ? kw2 : vw2; }
    else             { base = wsb + FC_OFF; mt = b - 48; W = xmw1; }
    const int ch = (mt & 7) * 16;
    u16 o[8];
#pragma unroll
    for (int j = 0; j < 8; ++j) o[j] = f2bf(W[(kt * 32 + lk * 8 + j) * 128 + ch + lr]);
    u32x4 pk;
#pragma unroll
    for (int i = 0; i < 4; ++i) pk[i] = (unsigned int)o[2 * i] | ((unsigned int)o[2 * i + 1] << 16);
    *(u32x4*)&base[((mt * 4 + kt) * 64 + l) * 8] = pk;
  } else {
    const int rt = b - 56;
    const int r = rt * 16 + lr;
    const float rel = (float)(r - 63);
    const int h0 = kt * 32 + lk * 8;
    float acc[8];
#pragma unroll
    for (int j = 0; j < 8; ++j) acc[j] = t_b[h0 + j];
    const float C = -logf(10000.0f) / 63.0f;
    for (int i = 0; i < 64; ++i) {
      float f = expf((float)i * C);
      float a = rel * f;
      float sn = sinf(a), cs = cosf(a);
#pragma unroll
      for (int j = 0; j < 8; ++j) acc[j] = fmaf(sn, t_w[i * 128 + h0 + j], acc[j]);
#pragma unroll
      for (int j = 0; j < 8; ++j) acc[j] = fmaf(cs, t_w[(i + 64) * 128 + h0 + j], acc[j]);
    }
    u16 o[8];
#pragma unroll
    for (int j = 0; j < 8; ++j) o[j] = f2bf(acc[j]);
    u32x4 pk;
#pragma unroll
    for (int i = 0; i < 4; ++i) pk[i] = (unsigned int)o[2 * i] | ((unsigned int)o[2 * i + 1] << 16);
    *(u32x4*)&wsb[FC_OFF + (((8 + rt) * 4 + kt) * 64 + l) * 8] = pk;
    const int ct = h0 >> 4, lrp = h0 & 15;
    const int ktp = r >> 5, lkp = (r >> 3) & 3, jp = r & 7;
#pragma unroll
    for (int j = 0; j < 8; ++j)
      wsb[FD_OFF + ((ct * 4 + ktp) * 64 + lkp * 16 + lrp + j) * 8 + jp] = o[j];
  }
}

static __device__ __forceinline__ void ldfrag(s8v* dst, const u16* __restrict__ base,
                                              int tile, int l) {
#pragma unroll
  for (int kt = 0; kt < 4; ++kt) dst[kt] = *(const s8v*)&base[tile * 2048 + kt * 512 + l * 8];
}

// 2-m-tile GEMM with B-frag register reuse: D tiles {mt0, mt0+1} x 64t
template <bool SILU, bool HASB>
static __device__ __forceinline__ void gemm2(const s8v* f0, const s8v* f1,
                                             const unsigned char* Bl, unsigned char* Ol,
                                             const float* __restrict__ bias, int mt0,
                                             int lr, int lk, int swm, const int* rb) {
  f4v acc[2][4];
#pragma unroll
  for (int mi = 0; mi < 2; ++mi) {
    float bj[4];
#pragma unroll
    for (int j = 0; j < 4; ++j) bj[j] = HASB ? bias[(mt0 + mi) * 16 + lk * 4 + j] : 0.f;
#pragma unroll
    for (int ni = 0; ni < 4; ++ni)
#pragma unroll
      for (int j = 0; j < 4; ++j) acc[mi][ni][j] = bj[j];
  }
  __builtin_amdgcn_s_setprio(1);
#pragma unroll
  for (int kt = 0; kt < 4; ++kt) {
    s8v a0 = f0[kt], a1 = f1[kt];
#pragma unroll
    for (int ni = 0; ni < 4; ++ni) {
      s8v b = *(const s8v*)(Bl + ni * 4096 + rb[kt]);
      acc[0][ni] = MFMA16(a0, b, acc[0][ni]);
      acc[1][ni] = MFMA16(a1, b, acc[1][ni]);
    }
  }
  __builtin_amdgcn_s_setprio(0);
#pragma unroll
  for (int mi = 0; mi < 2; ++mi) {
    const int ob = lr * 256 + ((((mt0 + mi) * 32) + lk * 8) ^ swm);
#pragma unroll
    for (int ni = 0; ni < 4; ++ni) {
      float v0 = acc[mi][ni][0], v1 = acc[mi][ni][1], v2 = acc[mi][ni][2], v3 = acc[mi][ni][3];
      if (SILU) { v0 = silu(v0); v1 = silu(v1); v2 = silu(v2); v3 = silu(v3); }
      u32x2 st; st[0] = cvt2u(v0, v1); st[1] = cvt2u(v2, v3);
      *(u32x2*)(Ol + ni * 4096 + ob) = st;
    }
  }
}

// LDS slots (16KB each, 80KB total -> 2 blocks/CU); liveness:
// S0: tok -> V     S1: HQ -> K      S2: HK -> {ALP(8K)|Y@8192|XLS@10240|VXP@11264}
// S3: HV -> qEc -> vT               S4: Q -> A2
__launch_bounds__(512, 4)
__global__ void et_main(const float* __restrict__ xg, const float* __restrict__ hg,
                        const u16* __restrict__ wsb,
                        const float* __restrict__ qb1, const float* __restrict__ qb2,
                        const float* __restrict__ kb1,
                        const float* __restrict__ vb1, const float* __restrict__ vb2,
                        const float* __restrict__ xmb1, const float* __restrict__ xmw2,
                        const float* __restrict__ xmb2,
                        float* __restrict__ xout, float* __restrict__ hout) {
  __shared__ __align__(16) unsigned char smem[81920];
  unsigned char* S0 = smem;
  unsigned char* S1 = smem + 16384;
  unsigned char* S2 = smem + 32768;
  unsigned char* S3 = smem + 49152;
  unsigned char* S4 = smem + 65536;
  unsigned char* ALP = S2;
  unsigned char* YB  = S2 + 8192;
  float* XLS = (float*)(S2 + 10240);
  float* VXP = (float*)(S2 + 11264);

  const u16* FA = wsb + FA_OFF;
  const u16* FB = wsb + FB_OFF;
  const u16* FC = wsb + FC_OFF;
  const u16* FD = wsb + FD_OFF;

  const int tid = threadIdx.x;
  const int l = tid & 63;
  const int lr = l & 15, lk = l >> 4;
  const int w = __builtin_amdgcn_readfirstlane(tid >> 6);
  const int u = w & 3;
  const bool lo = w < 4;
  const int ni0 = (w >> 2) * 2;      // P6 t-half
  const int mt0 = 2 * u;             // P6 ch-tile pair
  const int n = blockIdx.x;
  const size_t hbase = (size_t)n * 8192;
  const int swm = (lr & 7) << 4;
  int rb[4], hrb[2];
#pragma unroll
  for (int kt = 0; kt < 4; ++kt) rb[kt] = lr * 256 + ((kt * 64 + lk * 16) ^ swm);
#pragma unroll
  for (int kt = 0; kt < 2; ++kt) hrb[kt] = lr * 128 + ((kt * 64 + lk * 16) ^ swm);

  // ---- preload P1 A-frags, then P0: tok -> S0 ----
  s8v fq[4], fk[4], fv[4];
  ldfrag(fq, FA, w, l); ldfrag(fk, FA, 8 + w, l); ldfrag(fv, FA, 16 + w, l);
  {
    int t = tid & 63, c0 = (tid >> 6) * 2;
#pragma unroll
    for (int cc = 0; cc < 2; ++cc) {
      int c = c0 + cc;
      float hv[8];
#pragma unroll
      for (int j = 0; j < 8; ++j) hv[j] = hg[hbase + (size_t)(c * 8 + j) * 64 + t];
      u32x4 pk;
#pragma unroll
      for (int j = 0; j < 4; ++j) pk[j] = cvt2u(hv[2 * j], hv[2 * j + 1]);
      *(u32x4*)(S0 + SW(t, c * 16)) = pk;
    }
  }
  __syncthreads();

  // ---- P1: fused q1/k1/v1, shared B (tok) ----
  {
    f4v aq[4], ak[4], av[4];
#pragma unroll
    for (int ni = 0; ni < 4; ++ni)
#pragma unroll
      for (int j = 0; j < 4; ++j) {
        aq[ni][j] = qb1[w * 16 + lk * 4 + j];
        ak[ni][j] = kb1[w * 16 + lk * 4 + j];
        av[ni][j] = vb1[w * 16 + lk * 4 + j];
      }
    __builtin_amdgcn_s_setprio(1);
#pragma unroll
    for (int kt = 0; kt < 4; ++kt) {
      s8v a0 = fq[kt], a1 = fk[kt], a2 = fv[kt];
#pragma unroll
      for (int ni = 0; ni < 4; ++ni) {
        s8v b = *(const s8v*)(S0 + ni * 4096 + rb[kt]);
        aq[ni] = MFMA16(a0, b, aq[ni]);
        ak[ni] = MFMA16(a1, b, ak[ni]);
        av[ni] = MFMA16(a2, b, av[ni]);
      }
    }
    __builtin_amdgcn_s_setprio(0);
    const int ob = lr * 256 + ((w * 32 + lk * 8) ^ swm);
#pragma unroll
    for (int ni = 0; ni < 4; ++ni) {
      u32x2 s0v, s1v, s2v;
      s0v[0] = cvt2u(silu(aq[ni][0]), silu(aq[ni][1]));
      s0v[1] = cvt2u(silu(aq[ni][2]), silu(aq[ni][3]));
      s1v[0] = cvt2u(silu(ak[ni][0]), silu(ak[ni][1]));
      s1v[1] = cvt2u(silu(ak[ni][2]), silu(ak[ni][3]));
      s2v[0] = cvt2u(silu(av[ni][0]), silu(av[ni][1]));
      s2v[1] = cvt2u(silu(av[ni][2]), silu(av[ni][3]));
      *(u32x2*)(S1 + ni * 4096 + ob) = s0v;
      *(u32x2*)(S2 + ni * 4096 + ob) = s1v;
      *(u32x2*)(S3 + ni * 4096 + ob) = s2v;
    }
  }
  // preload P2 frags
  s8v fA0[4], fA1[4];
  if (lo) { ldfrag(fA0, FB, 2 * w, l);      ldfrag(fA1, FB, 2 * w + 1, l); }
  else    { ldfrag(fA0, FB, 16 + 2 * u, l); ldfrag(fA1, FB, 16 + 2 * u + 1, l); }
  __syncthreads();

  // ---- P2: q2 (w0-3: HQ->Q) || v2 (w4-7: HV->V) ----
  if (lo) gemm2<false, true>(fA0, fA1, S1, S4, qb2, 2 * w, lr, lk, swm, rb);
  else    gemm2<false, true>(fA0, fA1, S3, S0, vb2, 2 * u, lr, lk, swm, rb);
  // preload P3 frags
  if (lo) { ldfrag(fA0, FB, 8 + 2 * w, l); ldfrag(fA1, FB, 8 + 2 * w + 1, l); }
  else    { ldfrag(fA0, FC, 8 + 2 * u, l); ldfrag(fA1, FC, 8 + 2 * u + 1, l); }
  __syncthreads();

  // ---- P3: k2 (w0-3: HK->K, no bias: softmax-invariant) || qE compact (w4-7: Q->qEc S3) ----
  if (lo) {
    gemm2<false, false>(fA0, fA1, S2, S1, nullptr, 2 * w, lr, lk, swm, rb);
  } else {
    f4v acc[2][4];
#pragma unroll
    for (int mi = 0; mi < 2; ++mi)
#pragma unroll
      for (int ni = 0; ni < 4; ++ni)
#pragma unroll
        for (int j = 0; j < 4; ++j) acc[mi][ni][j] = 0.f;
    __builtin_amdgcn_s_setprio(1);
#pragma unroll
    for (int kt = 0; kt < 4; ++kt) {
      s8v a0 = fA0[kt], a1 = fA1[kt];
#pragma unroll
      for (int ni = 0; ni < 4; ++ni) {
        s8v b = *(const s8v*)(S4 + ni * 4096 + rb[kt]);
        acc[0][ni] = MFMA16(a0, b, acc[0][ni]);
        acc[1][ni] = MFMA16(a1, b, acc[1][ni]);
      }
    }
    __builtin_amdgcn_s_setprio(0);
#pragma unroll
    for (int mi = 0; mi < 2; ++mi) {
      const int rbase = (2 * u + mi) * 16 + lk * 4;
#pragma unroll
      for (int ni = 0; ni < 4; ++ni) {
        int t = ni * 16 + lr;
        unsigned int p0 = cvt2u(acc[mi][ni][0], acc[mi][ni][1]);
        unsigned int p1 = cvt2u(acc[mi][ni][2], acc[mi][ni][3]);
        int i0 = rbase - t;
        if ((unsigned)(i0 + 0) < 64u) *(u16*)(S3 + t * 128 + ((2 * (i0 + 0)) ^ swm)) = (u16)(p0 & 0xffffu);
        if ((unsigned)(i0 + 1) < 64u) *(u16*)(S3 + t * 128 + ((2 * (i0 + 1)) ^ swm)) = (u16)(p0 >> 16);
        if ((unsigned)(i0 + 2) < 64u) *(u16*)(S3 + t * 128 + ((2 * (i0 + 2)) ^ swm)) = (u16)(p1 & 0xffffu);
        if ((unsigned)(i0 + 3) < 64u) *(u16*)(S3 + t * 128 + ((2 * (i0 + 3)) ^ swm)) = (u16)(p1 >> 16);
      }
    }
  }
  // preload P4 frags (xm, hi waves only)
  if (!lo) { ldfrag(fA0, FC, 2 * u, l); ldfrag(fA1, FC, 2 * u + 1, l); }
  __syncthreads();

  // ---- P4: scores+softmax+ALP+A2 (w0-3) || xm->VXP (w4-7) ----
  if (lo) {
    const int n0 = w * 16, t = n0 + lr;
    s8v bq[4];
#pragma unroll
    for (int kt = 0; kt < 4; ++kt) bq[kt] = *(const s8v*)(S4 + n0 * 256 + rb[kt]);
    f4v acc[4];
#pragma unroll
    for (int mi = 0; mi < 4; ++mi)
#pragma unroll
      for (int j = 0; j < 4; ++j) acc[mi][j] = 0.f;
    __builtin_amdgcn_s_setprio(1);
#pragma unroll
    for (int kt = 0; kt < 4; ++kt)
#pragma unroll
      for (int mi = 0; mi < 4; ++mi)
        acc[mi] = MFMA16(*(const s8v*)(S1 + mi * 4096 + rb[kt]), bq[kt], acc[mi]);
    __builtin_amdgcn_s_setprio(0);
    float e[4][4];
#pragma unroll
    for (int mi = 0; mi < 4; ++mi) {
      u32x2 qv = *(const u32x2*)(S3 + t * 128 + ((120 - 32 * mi - 8 * lk) ^ swm));
      e[mi][3] = acc[mi][3] + bf2f((u16)(qv[0] & 0xffffu));
      e[mi][2] = acc[mi][2] + bf2f((u16)(qv[0] >> 16));
      e[mi][1] = acc[mi][1] + bf2f((u16)(qv[1] & 0xffffu));
      e[mi][0] = acc[mi][0] + bf2f((u16)(qv[1] >> 16));
    }
    float m = e[0][0];
#pragma unroll
    for (int mi = 0; mi < 4; ++mi)
#pragma unroll
      for (int j = 0; j < 4; ++j) m = fmaxf(m, e[mi][j]);
    m = fmaxf(m, __shfl_xor(m, 16, 64));
    m = fmaxf(m, __shfl_xor(m, 32, 64));
    float s = 0.f;
#pragma unroll
    for (int mi = 0; mi < 4; ++mi)
#pragma unroll
      for (int j = 0; j < 4; ++j) { e[mi][j] = __expf(e[mi][j] - m); s += e[mi][j]; }
    s += __shfl_xor(s, 16, 64);
    s += __shfl_xor(s, 32, 64);
    float inv = __builtin_amdgcn_rcpf(s);
    unsigned int apk[8];
#pragma unroll
    for (int mi = 0; mi < 4; ++mi) {
      apk[2 * mi]     = cvt2u(e[mi][0] * inv, e[mi][1] * inv);
      apk[2 * mi + 1] = cvt2u(e[mi][2] * inv, e[mi][3] * inv);
      u32x2 st; st[0] = apk[2 * mi]; st[1] = apk[2 * mi + 1];
      *(u32x2*)(ALP + t * 128 + ((mi * 32 + lk * 8) ^ swm)) = st;
    }
    // A2 zero (own rows; DS in-order after bq reads) + band scatter
    u32x4 zz; zz[0] = zz[1] = zz[2] = zz[3] = 0;
#pragma unroll
    for (int c = 0; c < 4; ++c) *(u32x4*)(S4 + t * 256 + lk * 64 + c * 16) = zz;
#pragma unroll
    for (int mi = 0; mi < 4; ++mi) {
      int rr = t + 63 - mi * 16 - lk * 4;
      *(u16*)(S4 + t * 256 + ((2 * (rr - 0)) ^ swm)) = (u16)(apk[2 * mi] & 0xffffu);
      *(u16*)(S4 + t * 256 + ((2 * (rr - 1)) ^ swm)) = (u16)(apk[2 * mi] >> 16);
      *(u16*)(S4 + t * 256 + ((2 * (rr - 2)) ^ swm)) = (u16)(apk[2 * mi + 1] & 0xffffu);
      *(u16*)(S4 + t * 256 + ((2 * (rr - 3)) ^ swm)) = (u16)(apk[2 * mi + 1] >> 16);
    }
  } else {
    // xm: 2 tiles over B=V(S0), vx partials -> VXP
    f4v acc[2][4];
#pragma unroll
    for (int mi = 0; mi < 2; ++mi)
#pragma unroll
      for (int ni = 0; ni < 4; ++ni)
#pragma unroll
        for (int j = 0; j < 4; ++j) acc[mi][ni][j] = xmb1[(2 * u + mi) * 16 + lk * 4 + j];
    __builtin_amdgcn_s_setprio(1);
#pragma unroll
    for (int kt = 0; kt < 4; ++kt) {
      s8v a0 = fA0[kt], a1 = fA1[kt];
#pragma unroll
      for (int ni = 0; ni < 4; ++ni) {
        s8v b = *(const s8v*)(S0 + ni * 4096 + rb[kt]);
        acc[0][ni] = MFMA16(a0, b, acc[0][ni]);
        acc[1][ni] = MFMA16(a1, b, acc[1][ni]);
      }
    }
    __builtin_amdgcn_s_setprio(0);
#pragma unroll
    for (int mi = 0; mi < 2; ++mi) {
      float w2[4];
#pragma unroll
      for (int j = 0; j < 4; ++j) w2[j] = xmw2[(2 * u + mi) * 16 + lk * 4 + j];
#pragma unroll
      for (int ni = 0; ni < 4; ++ni) {
        float s = 0.f;
#pragma unroll
        for (int j = 0; j < 4; ++j) s = fmaf(silu(acc[mi][ni][j]), w2[j], s);
        s += __shfl_xor(s, 16, 64);
        s += __shfl_xor(s, 32, 64);
        if (l < 16) VXP[(2 * u + mi) * 64 + ni * 16 + l] = s;
      }
    }
  }
  // preload P6 Erel^T frags
  s8v fd0[4], fd1[4];
  ldfrag(fd0, FD, mt0, l); ldfrag(fd1, FD, mt0 + 1, l);
  __syncthreads();

  // ---- P5: V transpose -> vT(S3) (w4-7); vx+Y+XLS (w0); Y zero (w1,w2); hld prefetch (all) ----
  float hld[16];
#pragma unroll
  for (int mi = 0; mi < 2; ++mi)
#pragma unroll
    for (int nj = 0; nj < 2; ++nj) {
      size_t base = hbase + (size_t)((mt0 + mi) * 16 + lk * 4) * 64 + (ni0 + nj) * 16 + lr;
#pragma unroll
      for (int j = 0; j < 4; ++j) hld[(mi * 2 + nj) * 4 + j] = hg[base + j * 64];
    }
  if (!lo) {
    const int t0 = (u & 1) * 32;
    const int c = ((u >> 1) << 6) + l;
    unsigned int pk[16];
#pragma unroll
    for (int i2 = 0; i2 < 16; ++i2) {
      int t = t0 + 2 * i2;
      u16 v0 = *(const u16*)(S0 + t * 256 + ((2 * c) ^ ((t & 7) << 4)));
      u16 v1 = *(const u16*)(S0 + (t + 1) * 256 + ((2 * c) ^ (((t + 1) & 7) << 4)));
      pk[i2] = (unsigned int)v0 | ((unsigned int)v1 << 16);
    }
    const int cm = (c & 7) << 4;
#pragma unroll
    for (int cc = 0; cc < 4; ++cc) {
      u32x4 st; st[0] = pk[4 * cc]; st[1] = pk[4 * cc + 1]; st[2] = pk[4 * cc + 2]; st[3] = pk[4 * cc + 3];
      *(u32x4*)(S3 + c * 128 + ((t0 * 2 + cc * 16) ^ cm)) = st;
    }
  } else if (w == 0) {
    int t = l;
    float vx = xmb2[0];
#pragma unroll
    for (int pt = 0; pt < 8; ++pt) vx += VXP[pt * 64 + t];
    float x0 = xg[n * 192 + t], x1 = xg[n * 192 + 64 + t], x2 = xg[n * 192 + 128 + t];
    XLS[t] = x0; XLS[64 + t] = x1; XLS[128 + t] = x2;
    unsigned int p0 = cvt2u(vx, vx * x0), p1 = cvt2u(vx * x1, vx * x2);
    *(u16*)(YB + 0   + ((2 * t) ^ 0))  = (u16)(p0 & 0xffffu);
    *(u16*)(YB + 128 + ((2 * t) ^ 16)) = (u16)(p0 >> 16);
    *(u16*)(YB + 256 + ((2 * t) ^ 32)) = (u16)(p1 & 0xffffu);
    *(u16*)(YB + 384 + ((2 * t) ^ 48)) = (u16)(p1 >> 16);
  } else if (w == 1) {
    u32x4 zz; zz[0] = zz[1] = zz[2] = zz[3] = 0;
    *(u32x4*)(YB + 512 + l * 16) = zz;
  } else if (w == 2) {
    if (l < 32) { u32x4 zz; zz[0] = zz[1] = zz[2] = zz[3] = 0; *(u32x4*)(YB + 1536 + l * 16) = zz; }
  }
  __syncthreads();

  // ---- P6: dh = alpha@v + A2@Erel (2m x 2n per wave); h_out; x update (w0-3) ----
  {
    f4v acc[2][2];
#pragma unroll
    for (int mi = 0; mi < 2; ++mi)
#pragma unroll
      for (int nj = 0; nj < 2; ++nj)
#pragma unroll
        for (int j = 0; j < 4; ++j) acc[mi][nj][j] = 0.f;
    __builtin_amdgcn_s_setprio(1);
#pragma unroll
    for (int kt = 0; kt < 2; ++kt) {
      s8v a0 = *(const s8v*)(S3 + (mt0)     * 2048 + hrb[kt]);
      s8v a1 = *(const s8v*)(S3 + (mt0 + 1) * 2048 + hrb[kt]);
#pragma unroll
      for (int nj = 0; nj < 2; ++nj) {
        s8v b = *(const s8v*)(ALP + (ni0 + nj) * 2048 + hrb[kt]);
        acc[0][nj] = MFMA16(a0, b, acc[0][nj]);
        acc[1][nj] = MFMA16(a1, b, acc[1][nj]);
      }
    }
#pragma unroll
    for (int kt = 0; kt < 4; ++kt) {
      s8v a0 = fd0[kt], a1 = fd1[kt];
#pragma unroll
      for (int nj = 0; nj < 2; ++nj) {
        s8v b = *(const s8v*)(S4 + (ni0 + nj) * 4096 + rb[kt]);
        acc[0][nj] = MFMA16(a0, b, acc[0][nj]);
        acc[1][nj] = MFMA16(a1, b, acc[1][nj]);
      }
    }
    __builtin_amdgcn_s_setprio(0);
#pragma unroll
    for (int mi = 0; mi < 2; ++mi)
#pragma unroll
      for (int nj = 0; nj < 2; ++nj) {
        size_t base = hbase + (size_t)((mt0 + mi) * 16 + lk * 4) * 64 + (ni0 + nj) * 16 + lr;
#pragma unroll
        for (int j = 0; j < 4; ++j)
          hout[base + j * 64] = hld[(mi * 2 + nj) * 4 + j] + acc[mi][nj][j];
      }
    if (lo) {
      f4v xa;
#pragma unroll
      for (int j = 0; j < 4; ++j) xa[j] = 0.f;
#pragma unroll
      for (int kt = 0; kt < 2; ++kt)
        xa = MFMA16(*(const s8v*)(YB + hrb[kt]),
                    *(const s8v*)(ALP + w * 2048 + hrb[kt]), xa);
      if (lk == 0) {
        int t = w * 16 + lr;
        float a1 = xa[0];
#pragma unroll
        for (int d = 0; d < 3; ++d) {
          float xv = XLS[d * 64 + t];
          xout[n * 192 + d * 64 + t] = fmaf(xv, a1, xv) - xa[1 + d];
        }
      }
    }
  }
}

extern "C" void kernel_launch(void* const* d_in, const int* in_sizes, int n_in,
                              void* d_out, int out_size, void* d_ws, size_t ws_size,
                              hipStream_t stream) {
  const float* xg   = (const float*)d_in[0];
  const float* hg   = (const float*)d_in[1];
  const float* qw1  = (const float*)d_in[2];
  const float* qb1  = (const float*)d_in[3];
  const float* qw2  = (const float*)d_in[4];
  const float* qb2  = (const float*)d_in[5];
  const float* kw1  = (const float*)d_in[6];
  const float* kb1  = (const float*)d_in[7];
  const float* kw2  = (const float*)d_in[8];
  const float* vw1  = (const float*)d_in[10];
  const float* vb1  = (const float*)d_in[11];
  const float* vw2  = (const float*)d_in[12];
  const float* vb2  = (const float*)d_in[13];
  const float* xmw1 = (const float*)d_in[14];
  const float* xmb1 = (const float*)d_in[15];
  const float* xmw2 = (const float*)d_in[16];
  const float* xmb2 = (const float*)d_in[17];
  const float* t_w  = (const float*)d_in[18];
  const float* t_b  = (const float*)d_in[19];

  u16* wsb = (u16*)d_ws;   // 294912 B
  float* xout = (float*)d_out;
  float* hout = xout + (size_t)NN * 192;

  prep_kernel<<<64, 256, 0, stream>>>(qw1, kw1, vw1, qw2, kw2, vw2, xmw1, t_w, t_b, wsb);
  et_main<<<NN, 512, 0, stream>>>(xg, hg, wsb,
                                  qb1, qb2, kb1, vb1, vb2, xmb1, xmw2, xmb2,
                                  xout, hout);
}